// Round 6
// baseline (481.522 us; speedup 1.0000x reference)
//
#include <hip/hip_runtime.h>

// ForwardDecoder: 2048x2048x3 softmax-HMM forward DP.
// R18 = R17 + (1) __launch_bounds__(256,1) [min 1 wave/EU -> full 512-VGPR
// budget for BOTH allocator and scheduler; R17's VGPR_Count=132 < the ~175
// live set implies the scheduler was serializing the 12 prefetch loads into
// a small destination pool, re-exposing VMEM latency each window],
// (2) s_setprio(1) on compute waves [transporters spin-poll VMEM on the same
// CU; bias CU scheduler toward compute], (3) division-free exp_pre (block
// per row) to cut the ~72us pre-work outside the DP.
// Carried from R17: unified compute body (all rings raw; IN expands bf16,
// OUT compresses), triple-buffered distance-2 register prefetch with KEEPQ
// pins, frexp renorms, skewed E' layout (RSTRIDE=6336, +2 pad rows).

typedef unsigned long long ull;
typedef float f4 __attribute__((ext_vector_type(4)));

#define LANES 64
#define NDIM 2048
#define MDIM 2048
#define BANDS 16
#define NWIN 132                 // (2048 + 64) / 16
#define NBOUND (BANDS - 1)
#define SLOT_ULL 18              // 16 cols + bias0 + bias1
#define NSLOTS 129
#define BOUND_ULL (NSLOTS * SLOT_ULL)
#define THMAXI (3 * NDIM * MDIM - 4)
#define RING 16
#define RSTRIDE (48 * NWIN)      // 6336 floats per skewed E' row
#define RSF4 (RSTRIDE / 4)       // 1584 float4 per E' row

#define WGSCOPE __HIP_MEMORY_SCOPE_WORKGROUP
#define LGKM0() asm volatile("s_waitcnt lgkmcnt(0)" ::: "memory")

__device__ __forceinline__ float rf(float x) {
    return __int_as_float(__builtin_amdgcn_readfirstlane(__float_as_int(x)));
}
__device__ __forceinline__ float ex2(float x) { return __builtin_amdgcn_exp2f(x); }
__device__ __forceinline__ float lg2(float x) { return __builtin_amdgcn_logf(x); }
__device__ __forceinline__ int clampi(int x, int lo, int hi) { return x < lo ? lo : (x > hi ? hi : x); }
__device__ __forceinline__ void ld16(f4* d, const float* p) { __builtin_memcpy(d, p, 16); }
__device__ __forceinline__ void schedbar() { __builtin_amdgcn_sched_barrier(0); }

#if __has_builtin(__builtin_amdgcn_update_dpp)
__device__ __forceinline__ float shup1(float x) {
    return __int_as_float(__builtin_amdgcn_update_dpp(
        0, __float_as_int(x), 0x138 /*wave_shr:1*/, 0xf, 0xf, true));
}
#else
__device__ __forceinline__ float shup1(float x) { return __shfl_up(x, 1); }
#endif

__device__ __forceinline__ ull ald(const ull* p) {
    return __hip_atomic_load(p, __ATOMIC_RELAXED, __HIP_MEMORY_SCOPE_AGENT);
}
__device__ __forceinline__ void ast(ull* p, ull v) {
    __hip_atomic_store(p, v, __ATOMIC_RELAXED, __HIP_MEMORY_SCOPE_AGENT);
}
__device__ __forceinline__ float lo_f(ull u) { return __int_as_float((int)(unsigned)u); }
__device__ __forceinline__ float hi_f(ull u) { return __int_as_float((int)(u >> 32)); }
__device__ __forceinline__ int   hi_i(ull u) { return (int)(u >> 32); }
__device__ __forceinline__ ull   pk(float x, int tag) {
    return ((ull)(unsigned)tag << 32) | (ull)(unsigned)__float_as_int(x);
}
__device__ __forceinline__ ull pkraw(float a, float b2) {
    return ((ull)(unsigned)__float_as_int(b2) << 32) | (ull)(unsigned)__float_as_int(a);
}
__device__ __forceinline__ unsigned bf1(float x) {
    unsigned u = __float_as_uint(x);
    return (u + 0x7FFFu + ((u >> 16) & 1u)) >> 16;
}
__device__ __forceinline__ ull pk2(float m, float i, int tag) {
    return ((ull)(unsigned)tag << 32) | (ull)(bf1(m) | (bf1(i) << 16));
}
__device__ __forceinline__ float bflo(ull u) { return __uint_as_float((unsigned)u << 16); }
__device__ __forceinline__ float bfhi(ull u) { return __uint_as_float((unsigned)u & 0xFFFF0000u); }

#define THV16(T, u, c) (T[(3*(u)+(c)) >> 2][(3*(u)+(c)) & 3])

// Pin a 12-f4 tile into registers HERE (forces the loads' counted waitcnt at
// this point and forbids sinking the loads past it).
#define KEEPQ(THQ) asm volatile("" :                                             \
    "+v"(THQ[0]), "+v"(THQ[1]), "+v"(THQ[2]),  "+v"(THQ[3]),                     \
    "+v"(THQ[4]), "+v"(THQ[5]), "+v"(THQ[6]),  "+v"(THQ[7]),                     \
    "+v"(THQ[8]), "+v"(THQ[9]), "+v"(THQ[10]), "+v"(THQ[11]))

// ---------------- PRE==1: aligned loads from skewed E' ----------------
// Per-lane slice at row*RSTRIDE + 48*wnext; 16B-aligned for every lane and
// window; in-bounds for wnext<=133 (E' padded by two rows).
#define THLOAD_P(THQ, wnext) {                                                   \
    const float* tp_ = theta + thRowBase + 48 * (wnext);                         \
    ld16(&THQ[0], tp_);       ld16(&THQ[1], tp_ + 4);  ld16(&THQ[2], tp_ + 8);   \
    ld16(&THQ[3], tp_ + 12);  ld16(&THQ[4], tp_ + 16); ld16(&THQ[5], tp_ + 20);  \
    ld16(&THQ[6], tp_ + 24);  ld16(&THQ[7], tp_ + 28); ld16(&THQ[8], tp_ + 32);  \
    ld16(&THQ[9], tp_ + 36);  ld16(&THQ[10], tp_ + 40); ld16(&THQ[11], tp_ + 44);\
}
// ---------------- PRE==0 fallback: clamped loads (always safe) --------------
#define THLOAD_C(THQ, wnext) {                                                   \
    int fidx_ = thRowBase + 3 * (16 * (wnext) - r);                              \
    ld16(&THQ[0], theta + clampi(fidx_,      0, THMAXI));                        \
    ld16(&THQ[1], theta + clampi(fidx_ + 4,  0, THMAXI));                        \
    ld16(&THQ[2], theta + clampi(fidx_ + 8,  0, THMAXI));                        \
    ld16(&THQ[3], theta + clampi(fidx_ + 12, 0, THMAXI));                        \
    ld16(&THQ[4], theta + clampi(fidx_ + 16, 0, THMAXI));                        \
    ld16(&THQ[5], theta + clampi(fidx_ + 20, 0, THMAXI));                        \
    ld16(&THQ[6], theta + clampi(fidx_ + 24, 0, THMAXI));                        \
    ld16(&THQ[7], theta + clampi(fidx_ + 28, 0, THMAXI));                        \
    ld16(&THQ[8], theta + clampi(fidx_ + 32, 0, THMAXI));                        \
    ld16(&THQ[9], theta + clampi(fidx_ + 36, 0, THMAXI));                        \
    ld16(&THQ[10], theta + clampi(fidx_ + 40, 0, THMAXI));                       \
    ld16(&THQ[11], theta + clampi(fidx_ + 44, 0, THMAXI));                       \
    if (row == NDIM - 1 && (wnext) == NWIN - 1)                                  \
        THV16(THQ, 14, 2) = theta[3 * NDIM * MDIM - 1];                          \
}
#define THLOAD(THQ, wnext)                                                       \
    if constexpr (PRE != 0) THLOAD_P(THQ, wnext) else THLOAD_C(THQ, wnext)

// producers (unified: raw into ringOut)
#define PRDF(u) { if (isP) ringOut[ori][u] = pkraw(dM, dI); }
#define PRDM(u) { if (isP && valid && w >= 3) ringOut[ori][u] = pkraw(dM, dI); }

#define STEP_F(u, X0v, D0v, X1v, D1v, CMv, CIv, PRDm) {                          \
    float nM = shup1(dM), nI = shup1(dI);                                        \
    nM = isC ? (CMv) : nM;  nI = isC ? (CIv) : nI;                               \
    float T0, T1, T2;                                                            \
    if constexpr (PRE != 0) {                                                    \
        T0 = THV16(THL, u, 0) * (X0v);                                           \
        T1 = THV16(THL, u, 1) * (X1v);                                           \
        T2 = THV16(THL, u, 2);                                                   \
    } else {                                                                     \
        T0 = ex2(fmaf(THV16(THL, u, 0), INVLN2, (D0v)));                         \
        T1 = ex2(fmaf(THV16(THL, u, 1), INVLN2, (D1v)));                         \
        T2 = ex2(THV16(THL, u, 2) * INVLN2);                                     \
    }                                                                            \
    float nv2 = T2 * fmaf(a22, v2, fmaf(v1, a21, v0 * a20));                     \
    v0 = T0 * prevM;  v1 = T1 * nI;  v2 = nv2;                                   \
    prevM = nM;                                                                  \
    dM = fmaf(v2, a02, fmaf(v1, a01, v0 * a00));                                 \
    dI = fmaf(v2, a12, fmaf(v1, a11, v0 * a10));                                 \
    PRDm(u)                                                                      \
}
#define STEP_M(u, X0v, D0v, X1v, D1v, CMv, CIv, PRDm) {                          \
    float nM = shup1(dM), nI = shup1(dI);                                        \
    nM = isC ? (CMv) : nM;  nI = isC ? (CIv) : nI;                               \
    bool valid = (unsigned)(j - 1) < (unsigned)MDIM;                             \
    float T0, T1, T2;                                                            \
    if constexpr (PRE != 0) {                                                    \
        T0 = THV16(THL, u, 0) * (X0v);                                           \
        T1 = THV16(THL, u, 1) * (X1v);                                           \
        T2 = THV16(THL, u, 2);                                                   \
    } else {                                                                     \
        T0 = ex2(fmaf(THV16(THL, u, 0), INVLN2, (D0v)));                         \
        T1 = ex2(fmaf(THV16(THL, u, 1), INVLN2, (D1v)));                         \
        T2 = ex2(THV16(THL, u, 2) * INVLN2);                                     \
    }                                                                            \
    float nv2 = T2 * fmaf(a22, v2, fmaf(v1, a21, v0 * a20));                     \
    float nv0 = T0 * prevM, nv1 = T1 * nI;                                       \
    v0 = valid ? nv0 : v0; v1 = valid ? nv1 : v1; v2 = valid ? nv2 : v2;         \
    prevM = nM;                                                                  \
    dM = fmaf(v2, a02, fmaf(v1, a01, v0 * a00));                                 \
    dI = fmaf(v2, a12, fmaf(v1, a11, v0 * a10));                                 \
    PRDm(u)                                                                      \
    j += 1;                                                                      \
}

// half 1: steps 0..7 consume carM, L[0..6]; half 2: steps 8..15 consume L[7..14]
#define GMR(k) lo_f(L[k])
#define GIR(k) hi_f(L[k])
#define STEPS_FIRST(STP, PRDm)                                                   \
    STP(0,  XP, dA, XQ, dB, carM, carI, PRDm)                                    \
    STP(1,  XQ, dB, XS, dC, GMR(0),  GIR(0),  PRDm)                              \
    STP(2,  XS, dC, XS, dC, GMR(1),  GIR(1),  PRDm)                              \
    STP(3,  XS, dC, XS, dC, GMR(2),  GIR(2),  PRDm)                              \
    STP(4,  XS, dC, XS, dC, GMR(3),  GIR(3),  PRDm)                              \
    STP(5,  XS, dC, XS, dC, GMR(4),  GIR(4),  PRDm)                              \
    STP(6,  XS, dC, XS, dC, GMR(5),  GIR(5),  PRDm)                              \
    STP(7,  XS, dC, XS, dC, GMR(6),  GIR(6),  PRDm)
#define STEPS_SECOND(STP, PRDm)                                                  \
    STP(8,  XP2, dA2, XQ2, dB2, GMR(7),  GIR(7),  PRDm)                          \
    STP(9,  XQ2, dB2, XS2, dC2, GMR(8),  GIR(8),  PRDm)                          \
    STP(10, XS2, dC2, XS2, dC2, GMR(9),  GIR(9),  PRDm)                          \
    STP(11, XS2, dC2, XS2, dC2, GMR(10), GIR(10), PRDm)                          \
    STP(12, XS2, dC2, XS2, dC2, GMR(11), GIR(11), PRDm)                          \
    STP(13, XS2, dC2, XS2, dC2, GMR(12), GIR(12), PRDm)                          \
    STP(14, XS2, dC2, XS2, dC2, GMR(13), GIR(13), PRDm)                          \
    STP(15, XS2, dC2, XS2, dC2, GMR(14), GIR(14), PRDm)

// Renorms via exponent extraction: e = exponent(mm), sc = 2^-e (bit-built),
// l = (float)e — exactly consistent pair (sc = 2^-l), no lg2/rcp trans ops.
#define MIDRENORM() {                                                            \
    float mm = v0 + v1 + v2;                                                     \
    bool g = mm > 1e-33f;                                                        \
    int ei = (int)((__float_as_uint(mm) >> 23) & 0xFFu) - 127;                   \
    float l  = g ? (float)ei : (Bup - B);                                        \
    float sc = g ? __uint_as_float((unsigned)(127 - ei) << 23) : 1.0f;           \
    v0 *= sc; v1 *= sc; v2 *= sc; dM *= sc; dI *= sc;                            \
    B += l;                                                                      \
    float lup = shup1(l);                                                        \
    float dOldM = fminf(Bup - B, 100.f);                                         \
    Bup += lup;                                                                  \
    float dNewM = fminf(Bup - B, 100.f);                                         \
    float dCarM = fminf(lo_f(L[16]) - B, 100.f);                                 \
    dA2 = isC ? dCarM : dOldM;                                                   \
    dB2 = isC ? dCarM : dNewM;                                                   \
    float dLive1 = fminf(lo_f(L[17]) - B, 100.f);                                \
    dC2 = isC ? dLive1 : dNewM;                                                  \
    dNewC = dNewM;                                                               \
    if constexpr (PRE != 0) { XP2 = ex2(dA2); XQ2 = ex2(dB2); XS2 = ex2(dC2); }  \
}
#define RENORM16() {                                                             \
    float mm = v0 + v1 + v2;                                                     \
    bool g = mm > 1e-33f;                                                        \
    int ei = (int)((__float_as_uint(mm) >> 23) & 0xFFu) - 127;                   \
    float l  = g ? (float)ei : (Bup - B);                                        \
    float sc = g ? __uint_as_float((unsigned)(127 - ei) << 23) : 1.0f;           \
    v0 *= sc; v1 *= sc; v2 *= sc; dM *= sc; dI *= sc;                            \
    B += l;                                                                      \
    float lup = shup1(l);                                                        \
    float dOld = fminf(Bup - B, 100.f);                                          \
    Bup += lup;                                                                  \
    float dNew = fminf(Bup - B, 100.f);                                          \
    carM = GMR(15); carI = GIR(15);                                              \
    float dCar = fminf(lo_f(L[17]) - B, 100.f);                                  \
    dA = isC ? dCar : dOld;                                                      \
    dB = isC ? dCar : dNew;                                                      \
    dNewC = dNew;                                                                \
}
// window-top: first-half dLive from the freshly loaded entry's bias0 (L[16])
#define XSETUP() {                                                               \
    float dLive0 = fminf(lo_f(L[16]) - B, 100.f);                                \
    dC = isC ? dLive0 : dNewC;                                                   \
    if constexpr (PRE != 0) { XP = ex2(dA); XQ = ex2(dB); XS = ex2(dC); }        \
}

#define LDSIN16(cond) {                                                          \
    if ((cond) && r == 0) {                                                      \
        int e_ = w + 1, ri_ = e_ & (RING - 1);                                   \
        while (__hip_atomic_load(&tagIn[ri_], __ATOMIC_ACQUIRE, WGSCOPE)         \
               != e_ + 1) {}                                                     \
        _Pragma("unroll")                                                        \
        for (int q_ = 0; q_ < 18; ++q_) L[q_] = ringIn[ri_][q_];                 \
        __hip_atomic_store(consIn, e_, __ATOMIC_RELAXED, WGSCOPE);               \
    }                                                                            \
}

// ---- unified compute window (both waves; THa=use, THb=pin, THc=load w+2) ----
#define WIN_F(THa, THb, THc) {                                                   \
    const f4* THL = (const f4*)(THa);                                            \
    LDSIN16(hasIn)                                                               \
    if (isP && w >= 19) {                                                        \
        while (__hip_atomic_load(gateDn, __ATOMIC_RELAXED, WGSCOPE)              \
               < w - 18) {}                                                      \
    }                                                                            \
    THLOAD(THc, w + 2)                                                           \
    XSETUP()                                                                     \
    schedbar();                                                                  \
    int ori = (w - 3) & (RING - 1);                                              \
    STEPS_FIRST(STEP_F, PRDF)                                                    \
    if (isP) ringOut[ori][16] = pkraw(B, 0.f);                                   \
    MIDRENORM()                                                                  \
    STEPS_SECOND(STEP_F, PRDF)                                                   \
    if (isP) {                                                                   \
        ringOut[ori][17] = pkraw(B, 0.f);                                        \
        LGKM0();                                                                 \
        __hip_atomic_store(&tagOut[ori], w - 2, __ATOMIC_RELAXED, WGSCOPE);      \
    }                                                                            \
    RENORM16()                                                                   \
    KEEPQ(THb);                                                                  \
    w++;                                                                         \
}
#define WIN_M(THa, THb, THc) {                                                   \
    const f4* THL = (const f4*)(THa);                                            \
    LDSIN16((hasIn && w <= 127))                                                 \
    if (isP && w >= 19) {                                                        \
        while (__hip_atomic_load(gateDn, __ATOMIC_RELAXED, WGSCOPE)              \
               < w - 18) {}                                                      \
    }                                                                            \
    THLOAD(THc, w + 2)                                                           \
    XSETUP()                                                                     \
    schedbar();                                                                  \
    int ori = (w - 3) & (RING - 1);                                              \
    STEPS_FIRST(STEP_M, PRDM)                                                    \
    if (isP && w >= 3) ringOut[ori][16] = pkraw(B, 0.f);                         \
    MIDRENORM()                                                                  \
    STEPS_SECOND(STEP_M, PRDM)                                                   \
    if (isP && w >= 3) {                                                         \
        ringOut[ori][17] = pkraw(B, 0.f);                                        \
        if (w < NWIN - 1) {                                                      \
            LGKM0();                                                             \
            __hip_atomic_store(&tagOut[ori], w - 2, __ATOMIC_RELAXED, WGSCOPE);  \
        }                                                                        \
    }                                                                            \
    RENORM16()                                                                   \
    KEEPQ(THb);                                                                  \
    w++;                                                                         \
}

// exp_pre v2: one block per row, division-free, coalesced.
// Writes skewed E' = 2^(theta/ln2): row stride RSTRIDE, row data shifted
// right by 3*(row%64), zero padding.
__global__ __launch_bounds__(256) void exp_pre(const float* __restrict__ th,
                                               float* __restrict__ E) {
    const float IV = 1.44269504088896340736f;
    const int rowi = blockIdx.x;
    const int shift = 3 * (rowi & 63);
    const float* src = th + (size_t)rowi * (3 * MDIM);
    f4* dst = (f4*)(E + (size_t)rowi * RSTRIDE);
    for (int fo4 = threadIdx.x; fo4 < RSF4; fo4 += 256) {
        int lo = fo4 * 4 - shift;
        f4 o;
        if (lo >= 0 && lo + 4 <= 3 * MDIM) {
            f4 x;
            ld16(&x, src + lo);
            o.x = ex2(x.x * IV); o.y = ex2(x.y * IV);
            o.z = ex2(x.z * IV); o.w = ex2(x.w * IV);
        } else {
            o.x = ((unsigned)lo       < (unsigned)(3 * MDIM)) ? ex2(src[lo]     * IV) : 0.f;
            o.y = ((unsigned)(lo + 1) < (unsigned)(3 * MDIM)) ? ex2(src[lo + 1] * IV) : 0.f;
            o.z = ((unsigned)(lo + 2) < (unsigned)(3 * MDIM)) ? ex2(src[lo + 2] * IV) : 0.f;
            o.w = ((unsigned)(lo + 3) < (unsigned)(3 * MDIM)) ? ex2(src[lo + 3] * IV) : 0.f;
        }
        dst[fo4] = o;
    }
}

template<int PRE>
__global__ __launch_bounds__(4 * LANES, 1)
__attribute__((amdgpu_waves_per_eu(1, 1)))
void fwd_hmm(const float* __restrict__ theta, const float* __restrict__ A,
             float* __restrict__ out, ull* __restrict__ chunks)
{
    __shared__ ull inRing[RING][18];
    __shared__ ull midRing[RING][18];
    __shared__ ull outRing[RING][18];
    __shared__ int inTag[RING];
    __shared__ int midTag[RING];
    __shared__ int outTag[RING];
    __shared__ int consW;
    __shared__ int midConsW;
    __shared__ int pushedW;

    const int b = blockIdx.x;
    const int tid = threadIdx.x;
    const int wv = tid >> 6;
    const int r = tid & 63;
    const bool bNot0 = (b != 0);

    if (tid == 0) {
        for (int i = 0; i < RING; ++i) { inTag[i] = 0; midTag[i] = 0; outTag[i] = 0; }
        consW = -1; midConsW = -1; pushedW = 0;
    }
    __syncthreads();

    if (wv == 2) {
        // ------ IN transporter: 3 slot-groups x 18 atoms; expands bf16->raw ------
        const int lane = r;
        const int g = lane / 18, q = lane - 18 * g;
        const bool crew = (lane < 54);
        const ull* up = chunks + (size_t)(bNot0 ? b - 1 : 0) * BOUND_ULL;
        int sIn = bNot0 ? 0 : NSLOTS;
        while (sIn < NSLOTS) {
            ull v = 0;
            int eIn = sIn + g;
            bool act = crew & (eIn < NSLOTS);
            if (act) v = ald(up + (size_t)eIn * SLOT_ULL + q);
            int cons = __hip_atomic_load(&consW, __ATOMIC_RELAXED, WGSCOPE);
            bool ok = false;
            if (act) {
                ok = (hi_i(v) == eIn + 1) | ((eIn == 0) & (q < 15));
                ok &= (eIn - cons) <= (RING - 1);
            }
            ull bal = __ballot(ok);
            int n = 0;
            while (n < 3 && ((bal >> (18 * n)) & 0x3FFFFull) == 0x3FFFFull) n++;
            if (n > 0) {
                ull vs = (q < 16) ? pkraw(bflo(v), bfhi(v)) : v;
                if ((g < n) & crew) inRing[eIn & (RING - 1)][q] = vs;
                if (lane == 0)
                    for (int k = 0; k < n; ++k)
                        __hip_atomic_store(&inTag[(sIn + k) & (RING - 1)],
                                           sIn + k + 1, __ATOMIC_RELEASE, WGSCOPE);
                sIn += n;
            } else __builtin_amdgcn_s_sleep(1);
        }
        return;
    }
    if (wv == 3) {
        // ------ OUT transporter: compresses raw->bf16 (+tags) on egress ------
        const int lane = r;
        const int g = lane / 18, q = lane - 18 * g;
        const bool crew = (lane < 54);
        ull* down = chunks + (size_t)(b < NBOUND ? b : 0) * BOUND_ULL;
        int sOut = (b != BANDS - 1) ? 0 : NSLOTS;
        while (sOut < NSLOTS) {
            int eO = sOut + g;
            bool rdy = false;
            if (crew & (eO < NSLOTS))
                rdy = (__hip_atomic_load(&outTag[eO & (RING - 1)],
                                         __ATOMIC_ACQUIRE, WGSCOPE) == eO + 1);
            ull bal = __ballot(rdy);
            int n = 0;
            while (n < 3 && ((bal >> (18 * n)) & 0x3FFFFull) == 0x3FFFFull) n++;
            if (n > 0) {
                if ((g < n) & crew) {
                    ull v = outRing[eO & (RING - 1)][q];
                    ull vs = (q < 16) ? pk2(lo_f(v), hi_f(v), eO + 1)
                                      : pk(lo_f(v), eO + 1);
                    ast(down + (size_t)eO * SLOT_ULL + q, vs);
                }
                sOut += n;
                if (lane == 0)
                    __hip_atomic_store(&pushedW, sOut, __ATOMIC_RELAXED, WGSCOPE);
            } else __builtin_amdgcn_s_sleep(1);
        }
        return;
    }

    // ---------------- unified compute waves (wv 0,1), 64 rows each ----------------
    __builtin_amdgcn_s_setprio(1);   // favor compute over spin-polling transporters
    const float INVLN2 = 1.44269504088896340736f;
    const float LN2    = 0.69314718055994530942f;
    const bool isC = (r == 0);

    float a00 = rf(expf(A[0])), a01 = rf(expf(A[1])), a02 = rf(expf(A[2]));
    float a10 = rf(expf(A[3])), a11 = rf(expf(A[4])), a12 = rf(expf(A[5]));
    float a20 = rf(expf(A[6])), a21 = rf(expf(A[7])), a22 = rf(expf(A[8]));

    float v0 = 0.f, v1 = 0.f, v2 = 0.f;
    float dM = 0.f, dI = 0.f;
    float B = 0.f, Bup = 0.f;
    float dA = 0.f, dB = 0.f, dC = 0.f, dNewC = 0.f;
    float dA2 = 0.f, dB2 = 0.f, dC2 = 0.f;
    float XP = 1.f, XQ = 1.f, XS = 1.f, XP2 = 1.f, XQ2 = 1.f, XS2 = 1.f;
    float carM = 0.f, carI = 0.f;
    ull L[18] = {};
    f4 TH0[12], TH1[12], TH2[12];

    // wave-role parameterization (one shared code path)
    ull (*ringIn)[18]  = (wv == 0) ? inRing  : midRing;
    ull (*ringOut)[18] = (wv == 0) ? midRing : outRing;
    int* tagIn   = (wv == 0) ? inTag  : midTag;
    int* tagOut  = (wv == 0) ? midTag : outTag;
    int* consIn  = (wv == 0) ? &consW    : &midConsW;
    int* gateDn  = (wv == 0) ? &midConsW : &pushedW;
    const bool hasIn = (wv == 1) || bNot0;

    const int row = b * 128 + 64 * wv + r;
    const int thRowBase = row * ((PRE != 0) ? RSTRIDE : (3 * MDIM));
    const bool isP = (r == LANES - 1) && ((wv == 0) || (b != BANDS - 1));
    float prevM = (b == 0 && wv == 0 && r == 0) ? (a00 + a01 + a02) : 0.f;

    // prologue: issue batches 0 and 1; pin batch 0
    THLOAD(TH0, 0)
    THLOAD(TH1, 1)

    float biasD = 0.f;
    if (hasIn && r == 0) {
        while (__hip_atomic_load(&tagIn[0], __ATOMIC_ACQUIRE, WGSCOPE) != 1) {}
        ull c15 = ringIn[0][15], c17 = ringIn[0][17];
        carM = lo_f(c15); carI = hi_f(c15);
        biasD = fminf(lo_f(c17), 100.f);
        __hip_atomic_store(consIn, 0, __ATOMIC_RELAXED, WGSCOPE);
    }
    dA = isC ? biasD : 0.f;
    dB = dA;
    KEEPQ(TH0);

    int w = 0;
    int j = 1 - r;
    // head M windows 0..3 (period-3 buffer rotation: use w%3, pin (w+1)%3, load (w+2)%3)
    WIN_M(TH0, TH1, TH2)
    WIN_M(TH1, TH2, TH0)
    WIN_M(TH2, TH0, TH1)
    WIN_M(TH0, TH1, TH2)
    // F windows 4..123 (40 x 3; starts at w=4 -> 4%3=1)
    for (int it = 0; it < 40; ++it) {
        WIN_F(TH1, TH2, TH0)
        WIN_F(TH2, TH0, TH1)
        WIN_F(TH0, TH1, TH2)
    }
    // tail M windows 124..131 (124%3=1)
    j = 16 * 124 + 1 - r;
    WIN_M(TH1, TH2, TH0)
    WIN_M(TH2, TH0, TH1)
    WIN_M(TH0, TH1, TH2)
    WIN_M(TH1, TH2, TH0)
    WIN_M(TH2, TH0, TH1)
    WIN_M(TH0, TH1, TH2)
    WIN_M(TH1, TH2, TH0)
    WIN_M(TH2, TH0, TH1)

    // entry 128 atom 15 (col 2049) never produced: dummy + tag commit
    if (isP) {
        ringOut[128 & (RING - 1)][15] = pkraw(0.f, 0.f);
        LGKM0();
        __hip_atomic_store(&tagOut[128 & (RING - 1)], 129, __ATOMIC_RELAXED, WGSCOPE);
    }

    if (wv == 1 && b == BANDS - 1 && r == LANES - 1) {
        out[0] = (B + lg2(v0 + v1 + v2)) * LN2;   // Vt, invariant under rescales
    }
}

extern "C" void kernel_launch(void* const* d_in, const int* in_sizes, int n_in,
                              void* d_out, int out_size, void* d_ws, size_t ws_size,
                              hipStream_t stream) {
    (void)in_sizes; (void)n_in; (void)out_size;
    const float* theta = (const float*)d_in[0];
    const float* A     = (const float*)d_in[1];
    float* out = (float*)d_out;
    ull* chunks = (ull*)d_ws;    // [15 boundaries][129 slots][18 x 8B atoms]
    size_t chunkB = (size_t)NBOUND * BOUND_ULL * sizeof(ull);
    hipMemsetAsync(chunks, 0, chunkB, stream);
    size_t eoff = (chunkB + 255) & ~(size_t)255;
    // +2 padding rows so the distance-2 tail prefetch (batch up to 133) stays in bounds
    size_t need = eoff + (size_t)(NDIM + 2) * RSTRIDE * sizeof(float);
    if (ws_size >= need) {
        float* E = (float*)((char*)d_ws + eoff);
        hipLaunchKernelGGL(exp_pre, dim3(NDIM), dim3(256), 0, stream, theta, E);
        hipLaunchKernelGGL((fwd_hmm<1>), dim3(BANDS), dim3(4 * LANES), 0, stream,
                           E, A, out, chunks);
    } else {
        hipLaunchKernelGGL((fwd_hmm<0>), dim3(BANDS), dim3(4 * LANES), 0, stream,
                           theta, A, out, chunks);
    }
}

// Round 7
// 470.687 us; speedup vs baseline: 1.0230x; 1.0230x over previous
//
#include <hip/hip_runtime.h>

// ForwardDecoder: 2048x2048x3 softmax-HMM forward DP.
// R19 = R18 with the theta prefetch converted to INLINE-ASM async loads.
// R18 post-mortem: KEEPQ "+v" pin only forces values live AT THE PIN -> the
// compiler sank the 12 loads to right before the pin (VGPR 132->108!), fully
// exposing ~900cyc VMEM latency per window. Source-level scheduling hints
// cannot express "issue now, wait later"; inline asm can:
//  - 12x global_load_dwordx4 (one addr reg + offset: immediates) per window,
//    double-buffered at distance 1. asm volatile order is preserved.
//  - window top: s_waitcnt vmcnt(0) retires batch w (issued a FULL WINDOW
//    earlier -> latency hidden) + sched_barrier(0) so uses can't hoist above
//    the wait (guide rule #18). Only-theta-VMEM makes vmcnt(0) exact.
//  - L ring copy via memcpy (9x ds_read_b128 instead of 18x b64).
//  - producer flow-gate read cached in a register (monotone counter).
// Carried: unified compute body, raw rings (IN expands/OUT compresses),
// frexp renorms, skewed E' (RSTRIDE=6336, +2 pad rows), division-free
// exp_pre, s_setprio(1), launch_bounds(256,1)+waves_per_eu(1,1).

typedef unsigned long long ull;
typedef float f4 __attribute__((ext_vector_type(4)));

#define LANES 64
#define NDIM 2048
#define MDIM 2048
#define BANDS 16
#define NWIN 132                 // (2048 + 64) / 16
#define NBOUND (BANDS - 1)
#define SLOT_ULL 18              // 16 cols + bias0 + bias1
#define NSLOTS 129
#define BOUND_ULL (NSLOTS * SLOT_ULL)
#define THMAXI (3 * NDIM * MDIM - 4)
#define RING 16
#define RSTRIDE (48 * NWIN)      // 6336 floats per skewed E' row
#define RSF4 (RSTRIDE / 4)       // 1584 float4 per E' row

#define WGSCOPE __HIP_MEMORY_SCOPE_WORKGROUP
#define LGKM0() asm volatile("s_waitcnt lgkmcnt(0)" ::: "memory")

__device__ __forceinline__ float rf(float x) {
    return __int_as_float(__builtin_amdgcn_readfirstlane(__float_as_int(x)));
}
__device__ __forceinline__ float ex2(float x) { return __builtin_amdgcn_exp2f(x); }
__device__ __forceinline__ float lg2(float x) { return __builtin_amdgcn_logf(x); }
__device__ __forceinline__ int clampi(int x, int lo, int hi) { return x < lo ? lo : (x > hi ? hi : x); }
__device__ __forceinline__ void ld16(f4* d, const float* p) { __builtin_memcpy(d, p, 16); }
__device__ __forceinline__ void schedbar() { __builtin_amdgcn_sched_barrier(0); }

#if __has_builtin(__builtin_amdgcn_update_dpp)
__device__ __forceinline__ float shup1(float x) {
    return __int_as_float(__builtin_amdgcn_update_dpp(
        0, __float_as_int(x), 0x138 /*wave_shr:1*/, 0xf, 0xf, true));
}
#else
__device__ __forceinline__ float shup1(float x) { return __shfl_up(x, 1); }
#endif

__device__ __forceinline__ ull ald(const ull* p) {
    return __hip_atomic_load(p, __ATOMIC_RELAXED, __HIP_MEMORY_SCOPE_AGENT);
}
__device__ __forceinline__ void ast(ull* p, ull v) {
    __hip_atomic_store(p, v, __ATOMIC_RELAXED, __HIP_MEMORY_SCOPE_AGENT);
}
__device__ __forceinline__ float lo_f(ull u) { return __int_as_float((int)(unsigned)u); }
__device__ __forceinline__ float hi_f(ull u) { return __int_as_float((int)(u >> 32)); }
__device__ __forceinline__ int   hi_i(ull u) { return (int)(u >> 32); }
__device__ __forceinline__ ull   pk(float x, int tag) {
    return ((ull)(unsigned)tag << 32) | (ull)(unsigned)__float_as_int(x);
}
__device__ __forceinline__ ull pkraw(float a, float b2) {
    return ((ull)(unsigned)__float_as_int(b2) << 32) | (ull)(unsigned)__float_as_int(a);
}
__device__ __forceinline__ unsigned bf1(float x) {
    unsigned u = __float_as_uint(x);
    return (u + 0x7FFFu + ((u >> 16) & 1u)) >> 16;
}
__device__ __forceinline__ ull pk2(float m, float i, int tag) {
    return ((ull)(unsigned)tag << 32) | (ull)(bf1(m) | (bf1(i) << 16));
}
__device__ __forceinline__ float bflo(ull u) { return __uint_as_float((unsigned)u << 16); }
__device__ __forceinline__ float bfhi(ull u) { return __uint_as_float((unsigned)u & 0xFFFF0000u); }

#define THV16(T, u, c) (T[(3*(u)+(c)) >> 2][(3*(u)+(c)) & 3])

// Pin a 12-f4 tile (PRE==0 fallback only).
#define KEEPQ(THQ) asm volatile("" :                                             \
    "+v"(THQ[0]), "+v"(THQ[1]), "+v"(THQ[2]),  "+v"(THQ[3]),                     \
    "+v"(THQ[4]), "+v"(THQ[5]), "+v"(THQ[6]),  "+v"(THQ[7]),                     \
    "+v"(THQ[8]), "+v"(THQ[9]), "+v"(THQ[10]), "+v"(THQ[11]))

// ---------------- PRE==1: inline-asm async loads from skewed E' -------------
// One 64-bit address + 12 offset-immediate dwordx4 loads. asm volatile keeps
// issue order; the matching s_waitcnt vmcnt(0) is at the NEXT window top.
#define GLD(d, p, o) asm volatile(                                               \
    "global_load_dwordx4 %0, %1, off offset:" #o : "=v"(d) : "v"(p));
#define ISSUE_P(THQ, wnext) {                                                    \
    const float* tp_ = theta + thRowBase + 48 * (wnext);                         \
    GLD(THQ[0],  tp_, 0)   GLD(THQ[1],  tp_, 16)  GLD(THQ[2],  tp_, 32)         \
    GLD(THQ[3],  tp_, 48)  GLD(THQ[4],  tp_, 64)  GLD(THQ[5],  tp_, 80)         \
    GLD(THQ[6],  tp_, 96)  GLD(THQ[7],  tp_, 112) GLD(THQ[8],  tp_, 128)        \
    GLD(THQ[9],  tp_, 144) GLD(THQ[10], tp_, 160) GLD(THQ[11], tp_, 176)        \
}
// retire the previous batch; fence compiler motion across the wait
#define VMWAIT() {                                                               \
    if constexpr (PRE != 0) {                                                    \
        asm volatile("s_waitcnt vmcnt(0)" ::: "memory");                         \
        schedbar();                                                              \
    }                                                                            \
}
// ---------------- PRE==0 fallback: clamped compiler loads -------------------
#define THLOAD_C(THQ, wnext) {                                                   \
    int fidx_ = thRowBase + 3 * (16 * (wnext) - r);                              \
    ld16(&THQ[0], theta + clampi(fidx_,      0, THMAXI));                        \
    ld16(&THQ[1], theta + clampi(fidx_ + 4,  0, THMAXI));                        \
    ld16(&THQ[2], theta + clampi(fidx_ + 8,  0, THMAXI));                        \
    ld16(&THQ[3], theta + clampi(fidx_ + 12, 0, THMAXI));                        \
    ld16(&THQ[4], theta + clampi(fidx_ + 16, 0, THMAXI));                        \
    ld16(&THQ[5], theta + clampi(fidx_ + 20, 0, THMAXI));                        \
    ld16(&THQ[6], theta + clampi(fidx_ + 24, 0, THMAXI));                        \
    ld16(&THQ[7], theta + clampi(fidx_ + 28, 0, THMAXI));                        \
    ld16(&THQ[8], theta + clampi(fidx_ + 32, 0, THMAXI));                        \
    ld16(&THQ[9], theta + clampi(fidx_ + 36, 0, THMAXI));                        \
    ld16(&THQ[10], theta + clampi(fidx_ + 40, 0, THMAXI));                       \
    ld16(&THQ[11], theta + clampi(fidx_ + 44, 0, THMAXI));                       \
    if (row == NDIM - 1 && (wnext) == NWIN - 1)                                  \
        THV16(THQ, 14, 2) = theta[3 * NDIM * MDIM - 1];                          \
}

// producers (unified: raw into ringOut)
#define PRDF(u) { if (isP) ringOut[ori][u] = pkraw(dM, dI); }
#define PRDM(u) { if (isP && valid && w >= 3) ringOut[ori][u] = pkraw(dM, dI); }

#define STEP_F(u, X0v, D0v, X1v, D1v, CMv, CIv, PRDm) {                          \
    float nM = shup1(dM), nI = shup1(dI);                                        \
    nM = isC ? (CMv) : nM;  nI = isC ? (CIv) : nI;                               \
    float T0, T1, T2;                                                            \
    if constexpr (PRE != 0) {                                                    \
        T0 = THV16(THL, u, 0) * (X0v);                                           \
        T1 = THV16(THL, u, 1) * (X1v);                                           \
        T2 = THV16(THL, u, 2);                                                   \
    } else {                                                                     \
        T0 = ex2(fmaf(THV16(THL, u, 0), INVLN2, (D0v)));                         \
        T1 = ex2(fmaf(THV16(THL, u, 1), INVLN2, (D1v)));                         \
        T2 = ex2(THV16(THL, u, 2) * INVLN2);                                     \
    }                                                                            \
    float nv2 = T2 * fmaf(a22, v2, fmaf(v1, a21, v0 * a20));                     \
    v0 = T0 * prevM;  v1 = T1 * nI;  v2 = nv2;                                   \
    prevM = nM;                                                                  \
    dM = fmaf(v2, a02, fmaf(v1, a01, v0 * a00));                                 \
    dI = fmaf(v2, a12, fmaf(v1, a11, v0 * a10));                                 \
    PRDm(u)                                                                      \
}
#define STEP_M(u, X0v, D0v, X1v, D1v, CMv, CIv, PRDm) {                          \
    float nM = shup1(dM), nI = shup1(dI);                                        \
    nM = isC ? (CMv) : nM;  nI = isC ? (CIv) : nI;                               \
    bool valid = (unsigned)(j - 1) < (unsigned)MDIM;                             \
    float T0, T1, T2;                                                            \
    if constexpr (PRE != 0) {                                                    \
        T0 = THV16(THL, u, 0) * (X0v);                                           \
        T1 = THV16(THL, u, 1) * (X1v);                                           \
        T2 = THV16(THL, u, 2);                                                   \
    } else {                                                                     \
        T0 = ex2(fmaf(THV16(THL, u, 0), INVLN2, (D0v)));                         \
        T1 = ex2(fmaf(THV16(THL, u, 1), INVLN2, (D1v)));                         \
        T2 = ex2(THV16(THL, u, 2) * INVLN2);                                     \
    }                                                                            \
    float nv2 = T2 * fmaf(a22, v2, fmaf(v1, a21, v0 * a20));                     \
    float nv0 = T0 * prevM, nv1 = T1 * nI;                                       \
    v0 = valid ? nv0 : v0; v1 = valid ? nv1 : v1; v2 = valid ? nv2 : v2;         \
    prevM = nM;                                                                  \
    dM = fmaf(v2, a02, fmaf(v1, a01, v0 * a00));                                 \
    dI = fmaf(v2, a12, fmaf(v1, a11, v0 * a10));                                 \
    PRDm(u)                                                                      \
    j += 1;                                                                      \
}

// half 1: steps 0..7 consume carM, L[0..6]; half 2: steps 8..15 consume L[7..14]
#define GMR(k) lo_f(L[k])
#define GIR(k) hi_f(L[k])
#define STEPS_FIRST(STP, PRDm)                                                   \
    STP(0,  XP, dA, XQ, dB, carM, carI, PRDm)                                    \
    STP(1,  XQ, dB, XS, dC, GMR(0),  GIR(0),  PRDm)                              \
    STP(2,  XS, dC, XS, dC, GMR(1),  GIR(1),  PRDm)                              \
    STP(3,  XS, dC, XS, dC, GMR(2),  GIR(2),  PRDm)                              \
    STP(4,  XS, dC, XS, dC, GMR(3),  GIR(3),  PRDm)                              \
    STP(5,  XS, dC, XS, dC, GMR(4),  GIR(4),  PRDm)                              \
    STP(6,  XS, dC, XS, dC, GMR(5),  GIR(5),  PRDm)                              \
    STP(7,  XS, dC, XS, dC, GMR(6),  GIR(6),  PRDm)
#define STEPS_SECOND(STP, PRDm)                                                  \
    STP(8,  XP2, dA2, XQ2, dB2, GMR(7),  GIR(7),  PRDm)                          \
    STP(9,  XQ2, dB2, XS2, dC2, GMR(8),  GIR(8),  PRDm)                          \
    STP(10, XS2, dC2, XS2, dC2, GMR(9),  GIR(9),  PRDm)                          \
    STP(11, XS2, dC2, XS2, dC2, GMR(10), GIR(10), PRDm)                          \
    STP(12, XS2, dC2, XS2, dC2, GMR(11), GIR(11), PRDm)                          \
    STP(13, XS2, dC2, XS2, dC2, GMR(12), GIR(12), PRDm)                          \
    STP(14, XS2, dC2, XS2, dC2, GMR(13), GIR(13), PRDm)                          \
    STP(15, XS2, dC2, XS2, dC2, GMR(14), GIR(14), PRDm)

// Renorms via exponent extraction: e = exponent(mm), sc = 2^-e (bit-built),
// l = (float)e — exactly consistent pair (sc = 2^-l), no lg2/rcp trans ops.
#define MIDRENORM() {                                                            \
    float mm = v0 + v1 + v2;                                                     \
    bool g = mm > 1e-33f;                                                        \
    int ei = (int)((__float_as_uint(mm) >> 23) & 0xFFu) - 127;                   \
    float l  = g ? (float)ei : (Bup - B);                                        \
    float sc = g ? __uint_as_float((unsigned)(127 - ei) << 23) : 1.0f;           \
    v0 *= sc; v1 *= sc; v2 *= sc; dM *= sc; dI *= sc;                            \
    B += l;                                                                      \
    float lup = shup1(l);                                                        \
    float dOldM = fminf(Bup - B, 100.f);                                         \
    Bup += lup;                                                                  \
    float dNewM = fminf(Bup - B, 100.f);                                         \
    float dCarM = fminf(lo_f(L[16]) - B, 100.f);                                 \
    dA2 = isC ? dCarM : dOldM;                                                   \
    dB2 = isC ? dCarM : dNewM;                                                   \
    float dLive1 = fminf(lo_f(L[17]) - B, 100.f);                                \
    dC2 = isC ? dLive1 : dNewM;                                                  \
    dNewC = dNewM;                                                               \
    if constexpr (PRE != 0) { XP2 = ex2(dA2); XQ2 = ex2(dB2); XS2 = ex2(dC2); }  \
}
#define RENORM16() {                                                             \
    float mm = v0 + v1 + v2;                                                     \
    bool g = mm > 1e-33f;                                                        \
    int ei = (int)((__float_as_uint(mm) >> 23) & 0xFFu) - 127;                   \
    float l  = g ? (float)ei : (Bup - B);                                        \
    float sc = g ? __uint_as_float((unsigned)(127 - ei) << 23) : 1.0f;           \
    v0 *= sc; v1 *= sc; v2 *= sc; dM *= sc; dI *= sc;                            \
    B += l;                                                                      \
    float lup = shup1(l);                                                        \
    float dOld = fminf(Bup - B, 100.f);                                          \
    Bup += lup;                                                                  \
    float dNew = fminf(Bup - B, 100.f);                                          \
    carM = GMR(15); carI = GIR(15);                                              \
    float dCar = fminf(lo_f(L[17]) - B, 100.f);                                  \
    dA = isC ? dCar : dOld;                                                      \
    dB = isC ? dCar : dNew;                                                      \
    dNewC = dNew;                                                                \
}
// window-top: first-half dLive from the freshly loaded entry's bias0 (L[16])
#define XSETUP() {                                                               \
    float dLive0 = fminf(lo_f(L[16]) - B, 100.f);                                \
    dC = isC ? dLive0 : dNewC;                                                   \
    if constexpr (PRE != 0) { XP = ex2(dA); XQ = ex2(dB); XS = ex2(dC); }        \
}

#define LDSIN16(cond) {                                                          \
    if ((cond) && r == 0) {                                                      \
        int e_ = w + 1, ri_ = e_ & (RING - 1);                                   \
        while (__hip_atomic_load(&tagIn[ri_], __ATOMIC_ACQUIRE, WGSCOPE)         \
               != e_ + 1) {}                                                     \
        __builtin_memcpy(&L[0], (const void*)&ringIn[ri_][0], 144);              \
        __hip_atomic_store(consIn, e_, __ATOMIC_RELAXED, WGSCOPE);               \
    }                                                                            \
}
// producer flow gate with cached monotone counter (LDS poll only when needed)
#define GATEPOLL() {                                                             \
    if (isP && w >= 19 && gateCache < w - 18) {                                  \
        do {                                                                     \
            gateCache = __hip_atomic_load(gateDn, __ATOMIC_RELAXED, WGSCOPE);    \
        } while (gateCache < w - 18);                                            \
    }                                                                            \
}

// ---- unified compute window (both waves; THa = use, THb = issue w+1) ----
#define WIN_F(THa, THb) {                                                        \
    const f4* THL = (const f4*)(THa);                                            \
    LDSIN16(hasIn)                                                               \
    GATEPOLL()                                                                   \
    VMWAIT()                                                                     \
    if constexpr (PRE != 0) { ISSUE_P(THb, w + 1) } else { THLOAD_C(THb, w + 1) }\
    XSETUP()                                                                     \
    schedbar();                                                                  \
    int ori = (w - 3) & (RING - 1);                                              \
    STEPS_FIRST(STEP_F, PRDF)                                                    \
    if (isP) ringOut[ori][16] = pkraw(B, 0.f);                                   \
    MIDRENORM()                                                                  \
    STEPS_SECOND(STEP_F, PRDF)                                                   \
    if (isP) {                                                                   \
        ringOut[ori][17] = pkraw(B, 0.f);                                        \
        LGKM0();                                                                 \
        __hip_atomic_store(&tagOut[ori], w - 2, __ATOMIC_RELAXED, WGSCOPE);      \
    }                                                                            \
    RENORM16()                                                                   \
    if constexpr (PRE == 0) { KEEPQ(THb); }                                      \
    w++;                                                                         \
}
#define WIN_M(THa, THb) {                                                        \
    const f4* THL = (const f4*)(THa);                                            \
    LDSIN16((hasIn && w <= 127))                                                 \
    GATEPOLL()                                                                   \
    VMWAIT()                                                                     \
    if constexpr (PRE != 0) { ISSUE_P(THb, w + 1) } else { THLOAD_C(THb, w + 1) }\
    XSETUP()                                                                     \
    schedbar();                                                                  \
    int ori = (w - 3) & (RING - 1);                                              \
    STEPS_FIRST(STEP_M, PRDM)                                                    \
    if (isP && w >= 3) ringOut[ori][16] = pkraw(B, 0.f);                         \
    MIDRENORM()                                                                  \
    STEPS_SECOND(STEP_M, PRDM)                                                   \
    if (isP && w >= 3) {                                                         \
        ringOut[ori][17] = pkraw(B, 0.f);                                        \
        if (w < NWIN - 1) {                                                      \
            LGKM0();                                                             \
            __hip_atomic_store(&tagOut[ori], w - 2, __ATOMIC_RELAXED, WGSCOPE);  \
        }                                                                        \
    }                                                                            \
    RENORM16()                                                                   \
    if constexpr (PRE == 0) { KEEPQ(THb); }                                      \
    w++;                                                                         \
}

// exp_pre v2: one block per row, division-free, coalesced.
// Writes skewed E' = 2^(theta/ln2): row stride RSTRIDE, row data shifted
// right by 3*(row%64), zero padding.
__global__ __launch_bounds__(256) void exp_pre(const float* __restrict__ th,
                                               float* __restrict__ E) {
    const float IV = 1.44269504088896340736f;
    const int rowi = blockIdx.x;
    const int shift = 3 * (rowi & 63);
    const float* src = th + (size_t)rowi * (3 * MDIM);
    f4* dst = (f4*)(E + (size_t)rowi * RSTRIDE);
    for (int fo4 = threadIdx.x; fo4 < RSF4; fo4 += 256) {
        int lo = fo4 * 4 - shift;
        f4 o;
        if (lo >= 0 && lo + 4 <= 3 * MDIM) {
            f4 x;
            ld16(&x, src + lo);
            o.x = ex2(x.x * IV); o.y = ex2(x.y * IV);
            o.z = ex2(x.z * IV); o.w = ex2(x.w * IV);
        } else {
            o.x = ((unsigned)lo       < (unsigned)(3 * MDIM)) ? ex2(src[lo]     * IV) : 0.f;
            o.y = ((unsigned)(lo + 1) < (unsigned)(3 * MDIM)) ? ex2(src[lo + 1] * IV) : 0.f;
            o.z = ((unsigned)(lo + 2) < (unsigned)(3 * MDIM)) ? ex2(src[lo + 2] * IV) : 0.f;
            o.w = ((unsigned)(lo + 3) < (unsigned)(3 * MDIM)) ? ex2(src[lo + 3] * IV) : 0.f;
        }
        dst[fo4] = o;
    }
}

template<int PRE>
__global__ __launch_bounds__(4 * LANES, 1)
__attribute__((amdgpu_waves_per_eu(1, 1)))
void fwd_hmm(const float* __restrict__ theta, const float* __restrict__ A,
             float* __restrict__ out, ull* __restrict__ chunks)
{
    __shared__ ull inRing[RING][18];
    __shared__ ull midRing[RING][18];
    __shared__ ull outRing[RING][18];
    __shared__ int inTag[RING];
    __shared__ int midTag[RING];
    __shared__ int outTag[RING];
    __shared__ int consW;
    __shared__ int midConsW;
    __shared__ int pushedW;

    const int b = blockIdx.x;
    const int tid = threadIdx.x;
    const int wv = tid >> 6;
    const int r = tid & 63;
    const bool bNot0 = (b != 0);

    if (tid == 0) {
        for (int i = 0; i < RING; ++i) { inTag[i] = 0; midTag[i] = 0; outTag[i] = 0; }
        consW = -1; midConsW = -1; pushedW = 0;
    }
    __syncthreads();

    if (wv == 2) {
        // ------ IN transporter: 3 slot-groups x 18 atoms; expands bf16->raw ------
        const int lane = r;
        const int g = lane / 18, q = lane - 18 * g;
        const bool crew = (lane < 54);
        const ull* up = chunks + (size_t)(bNot0 ? b - 1 : 0) * BOUND_ULL;
        int sIn = bNot0 ? 0 : NSLOTS;
        while (sIn < NSLOTS) {
            ull v = 0;
            int eIn = sIn + g;
            bool act = crew & (eIn < NSLOTS);
            if (act) v = ald(up + (size_t)eIn * SLOT_ULL + q);
            int cons = __hip_atomic_load(&consW, __ATOMIC_RELAXED, WGSCOPE);
            bool ok = false;
            if (act) {
                ok = (hi_i(v) == eIn + 1) | ((eIn == 0) & (q < 15));
                ok &= (eIn - cons) <= (RING - 1);
            }
            ull bal = __ballot(ok);
            int n = 0;
            while (n < 3 && ((bal >> (18 * n)) & 0x3FFFFull) == 0x3FFFFull) n++;
            if (n > 0) {
                ull vs = (q < 16) ? pkraw(bflo(v), bfhi(v)) : v;
                if ((g < n) & crew) inRing[eIn & (RING - 1)][q] = vs;
                if (lane == 0)
                    for (int k = 0; k < n; ++k)
                        __hip_atomic_store(&inTag[(sIn + k) & (RING - 1)],
                                           sIn + k + 1, __ATOMIC_RELEASE, WGSCOPE);
                sIn += n;
            } else __builtin_amdgcn_s_sleep(1);
        }
        return;
    }
    if (wv == 3) {
        // ------ OUT transporter: compresses raw->bf16 (+tags) on egress ------
        const int lane = r;
        const int g = lane / 18, q = lane - 18 * g;
        const bool crew = (lane < 54);
        ull* down = chunks + (size_t)(b < NBOUND ? b : 0) * BOUND_ULL;
        int sOut = (b != BANDS - 1) ? 0 : NSLOTS;
        while (sOut < NSLOTS) {
            int eO = sOut + g;
            bool rdy = false;
            if (crew & (eO < NSLOTS))
                rdy = (__hip_atomic_load(&outTag[eO & (RING - 1)],
                                         __ATOMIC_ACQUIRE, WGSCOPE) == eO + 1);
            ull bal = __ballot(rdy);
            int n = 0;
            while (n < 3 && ((bal >> (18 * n)) & 0x3FFFFull) == 0x3FFFFull) n++;
            if (n > 0) {
                if ((g < n) & crew) {
                    ull v = outRing[eO & (RING - 1)][q];
                    ull vs = (q < 16) ? pk2(lo_f(v), hi_f(v), eO + 1)
                                      : pk(lo_f(v), eO + 1);
                    ast(down + (size_t)eO * SLOT_ULL + q, vs);
                }
                sOut += n;
                if (lane == 0)
                    __hip_atomic_store(&pushedW, sOut, __ATOMIC_RELAXED, WGSCOPE);
            } else __builtin_amdgcn_s_sleep(1);
        }
        return;
    }

    // ---------------- unified compute waves (wv 0,1), 64 rows each ----------------
    __builtin_amdgcn_s_setprio(1);   // favor compute over spin-polling transporters
    const float INVLN2 = 1.44269504088896340736f;
    const float LN2    = 0.69314718055994530942f;
    const bool isC = (r == 0);

    float a00 = rf(expf(A[0])), a01 = rf(expf(A[1])), a02 = rf(expf(A[2]));
    float a10 = rf(expf(A[3])), a11 = rf(expf(A[4])), a12 = rf(expf(A[5]));
    float a20 = rf(expf(A[6])), a21 = rf(expf(A[7])), a22 = rf(expf(A[8]));

    float v0 = 0.f, v1 = 0.f, v2 = 0.f;
    float dM = 0.f, dI = 0.f;
    float B = 0.f, Bup = 0.f;
    float dA = 0.f, dB = 0.f, dC = 0.f, dNewC = 0.f;
    float dA2 = 0.f, dB2 = 0.f, dC2 = 0.f;
    float XP = 1.f, XQ = 1.f, XS = 1.f, XP2 = 1.f, XQ2 = 1.f, XS2 = 1.f;
    float carM = 0.f, carI = 0.f;
    int gateCache = 0;
    ull L[18] = {};
    f4 TH0[12], TH1[12];

    // wave-role parameterization (one shared code path)
    ull (*ringIn)[18]  = (wv == 0) ? inRing  : midRing;
    ull (*ringOut)[18] = (wv == 0) ? midRing : outRing;
    int* tagIn   = (wv == 0) ? inTag  : midTag;
    int* tagOut  = (wv == 0) ? midTag : outTag;
    int* consIn  = (wv == 0) ? &consW    : &midConsW;
    int* gateDn  = (wv == 0) ? &midConsW : &pushedW;
    const bool hasIn = (wv == 1) || bNot0;

    const int row = b * 128 + 64 * wv + r;
    const int thRowBase = row * ((PRE != 0) ? RSTRIDE : (3 * MDIM));
    const bool isP = (r == LANES - 1) && ((wv == 0) || (b != BANDS - 1));
    float prevM = (b == 0 && wv == 0 && r == 0) ? (a00 + a01 + a02) : 0.f;

    // prologue: issue batch 0 (retired by window 0's VMWAIT)
    if constexpr (PRE != 0) { ISSUE_P(TH0, 0) } else { THLOAD_C(TH0, 0) }

    float biasD = 0.f;
    if (hasIn && r == 0) {
        while (__hip_atomic_load(&tagIn[0], __ATOMIC_ACQUIRE, WGSCOPE) != 1) {}
        ull c15 = ringIn[0][15], c17 = ringIn[0][17];
        carM = lo_f(c15); carI = hi_f(c15);
        biasD = fminf(lo_f(c17), 100.f);
        __hip_atomic_store(consIn, 0, __ATOMIC_RELAXED, WGSCOPE);
    }
    dA = isC ? biasD : 0.f;
    dB = dA;
    if constexpr (PRE == 0) { KEEPQ(TH0); }

    int w = 0;
    int j = 1 - r;
    // head M windows 0..3
    for (int it = 0; it < 2; ++it) { WIN_M(TH0, TH1) WIN_M(TH1, TH0) }
    // F windows 4..123
    for (int it = 0; it < 60; ++it) { WIN_F(TH0, TH1) WIN_F(TH1, TH0) }
    // tail M windows 124..131
    j = 16 * 124 + 1 - r;
    for (int it = 0; it < 4; ++it) { WIN_M(TH0, TH1) WIN_M(TH1, TH0) }

    // entry 128 atom 15 (col 2049) never produced: dummy + tag commit
    if (isP) {
        ringOut[128 & (RING - 1)][15] = pkraw(0.f, 0.f);
        LGKM0();
        __hip_atomic_store(&tagOut[128 & (RING - 1)], 129, __ATOMIC_RELAXED, WGSCOPE);
    }

    if (wv == 1 && b == BANDS - 1 && r == LANES - 1) {
        out[0] = (B + lg2(v0 + v1 + v2)) * LN2;   // Vt, invariant under rescales
    }
}

extern "C" void kernel_launch(void* const* d_in, const int* in_sizes, int n_in,
                              void* d_out, int out_size, void* d_ws, size_t ws_size,
                              hipStream_t stream) {
    (void)in_sizes; (void)n_in; (void)out_size;
    const float* theta = (const float*)d_in[0];
    const float* A     = (const float*)d_in[1];
    float* out = (float*)d_out;
    ull* chunks = (ull*)d_ws;    // [15 boundaries][129 slots][18 x 8B atoms]
    size_t chunkB = (size_t)NBOUND * BOUND_ULL * sizeof(ull);
    hipMemsetAsync(chunks, 0, chunkB, stream);
    size_t eoff = (chunkB + 255) & ~(size_t)255;
    // +2 padding rows so the tail prefetch (batch up to 132) stays in bounds
    size_t need = eoff + (size_t)(NDIM + 2) * RSTRIDE * sizeof(float);
    if (ws_size >= need) {
        float* E = (float*)((char*)d_ws + eoff);
        hipLaunchKernelGGL(exp_pre, dim3(NDIM), dim3(256), 0, stream, theta, E);
        hipLaunchKernelGGL((fwd_hmm<1>), dim3(BANDS), dim3(4 * LANES), 0, stream,
                           E, A, out, chunks);
    } else {
        hipLaunchKernelGGL((fwd_hmm<0>), dim3(BANDS), dim3(4 * LANES), 0, stream,
                           theta, A, out, chunks);
    }
}